// Round 1
// baseline (522.920 us; speedup 1.0000x reference)
//
#include <hip/hip_runtime.h>

// HiddenMarkovGFormulaV2: N independent sequential filters over T=64 steps.
// Memory-bound streaming problem (~518 MB ideal traffic -> ~82 us floor).
//
// Strategy: 256 threads/block, one thread per individual n.
// Data layout is (N,T) row-major -> per-thread direct loads would be
// stride-256B across lanes. Instead cooperatively load (256 n x 16 t) tiles
// as float4 (16 aligned 64B segments per wave), transpose into LDS [t][n],
// compute the scan reading LDS stride-1, stage outputs in-place (each (t,n)
// slot is owned by exactly one thread), cooperatively store float4 back.

#define TT 64          // timesteps (fixed by reference)
#define KK 3           // covariates (fixed by reference)
#define NB 256         // individuals per block == block size
#define CT 16          // timesteps per LDS tile
#define LDP (NB + 4)   // LDS leading-dim pad: 260 mod 32 == 4 -> 2-way (free)

__global__ void zero_ll_kernel(float* ll) { *ll = 0.0f; }

__global__ __launch_bounds__(NB) void hmm_filter_kernel(
    const float* __restrict__ G,   // (N,1)
    const float* __restrict__ S,   // (N,T)
    const float* __restrict__ C,   // (N,T)
    const float* __restrict__ Y,   // (N,T)
    const float* __restrict__ L,   // (N,K)
    const float* __restrict__ p_psi,
    const float* __restrict__ p_gS,
    const float* __restrict__ p_gC,
    const float* __restrict__ p_gG,
    const float* __restrict__ p_gGS,
    const float* __restrict__ p_gGC,
    const float* __restrict__ p_gLw,  // (1,K)
    const float* __restrict__ p_lsZ,
    const float* __restrict__ p_b0,
    const float* __restrict__ p_bZ,
    const float* __restrict__ p_bS,
    const float* __restrict__ p_bG,
    const float* __restrict__ p_bGS,
    const float* __restrict__ p_bLw,  // (1,K)
    float* __restrict__ Zf,           // (N,T)
    float* __restrict__ Zv,           // (N,T)
    float* __restrict__ ll_out,       // scalar
    int N)
{
    __shared__ float sS[CT][LDP];
    __shared__ float sC[CT][LDP];
    __shared__ float sY[CT][LDP];
    __shared__ float wave_ll[NB / 64];

    const int tid = threadIdx.x;
    const int n0  = blockIdx.x * NB;
    const int n   = n0 + tid;
    const bool valid = (n < N);

    // --- uniform parameters (scalar-cached broadcast loads) ---
    const float psi  = p_psi[0];
    const float gS   = p_gS[0];
    const float gC   = p_gC[0];
    const float gG   = p_gG[0];
    const float gGS  = p_gGS[0];
    const float gGC  = p_gGC[0];
    const float b0   = p_b0[0];
    const float bZ   = p_bZ[0];
    const float bS   = p_bS[0];
    const float bG   = p_bG[0];
    const float bGS  = p_bGS[0];
    const float esz  = expf(p_lsZ[0]);
    const float sigma2 = esz * esz;
    const float psi2 = psi * psi;
    const float bZ2  = bZ * bZ;
    const float gw0 = p_gLw[0], gw1 = p_gLw[1], gw2 = p_gLw[2];
    const float bw0 = p_bLw[0], bw1 = p_bLw[1], bw2 = p_bLw[2];

    // --- per-n constants ---
    float Gv = 0.0f, gL = 0.0f, bL = 0.0f;
    if (valid) {
        Gv = G[n];
        const float l0 = L[n * KK + 0];
        const float l1 = L[n * KK + 1];
        const float l2 = L[n * KK + 2];
        gL = l0 * gw0 + l1 * gw1 + l2 * gw2;
        bL = l0 * bw0 + l1 * bw1 + l2 * bw2;
    }

    float zm = 0.0f;   // Z_mean
    float zv = 1.0f;   // Z_var
    float ll = 0.0f;

    const float4* S4 = (const float4*)S;
    const float4* C4 = (const float4*)C;
    const float4* Y4 = (const float4*)Y;
    float4* Zf4 = (float4*)Zf;
    float4* Zv4 = (float4*)Zv;

    for (int t0 = 0; t0 < TT; t0 += CT) {
        // --- cooperative load: NB rows x CT floats, float4-granular ---
        // q indexes NB*CT/4 float4s; r = row (n-local), c = which float4 in row.
        #pragma unroll
        for (int q = tid; q < NB * CT / 4; q += NB) {
            const int r  = q >> 2;      // CT/4 == 4 float4 per row
            const int c  = q & 3;
            const int nn = n0 + r;
            float4 vs, vc, vy;
            if (nn < N) {
                const int gidx = nn * (TT / 4) + (t0 >> 2) + c;
                vs = S4[gidx];
                vc = C4[gidx];
                vy = Y4[gidx];
            } else {
                vs = make_float4(0, 0, 0, 0);
                vc = vs; vy = vs;
            }
            const int tb = c * 4;
            sS[tb + 0][r] = vs.x; sS[tb + 1][r] = vs.y;
            sS[tb + 2][r] = vs.z; sS[tb + 3][r] = vs.w;
            sC[tb + 0][r] = vc.x; sC[tb + 1][r] = vc.y;
            sC[tb + 2][r] = vc.z; sC[tb + 3][r] = vc.w;
            sY[tb + 0][r] = vy.x; sY[tb + 1][r] = vy.y;
            sY[tb + 2][r] = vy.z; sY[tb + 3][r] = vy.w;
        }
        __syncthreads();

        // --- sequential filter over this tile's CT steps ---
        // Each (t, tid) LDS slot is read and then overwritten by exactly
        // this thread -> in-place output staging is race-free.
        #pragma unroll
        for (int t = 0; t < CT; ++t) {
            const float s = sS[t][tid];
            const float c = sC[t][tid];
            const float y = sY[t][tid];

            const float zpred = psi * zm + gS * s + gG * Gv + gC * c
                              + gGS * (Gv * s) + gGC * (Gv * c) + gL;
            const float zpvar = psi2 * zv + sigma2;

            float logit = b0 + bZ * zpred + bS * s + bG * Gv
                        + bGS * (Gv * s) + bL;
            logit = fminf(fmaxf(logit, -20.0f), 20.0f);
            const float p = 1.0f / (1.0f + expf(-logit));

            const float grad = (y - p) * bZ;
            const float hess = bZ2 * p * (1.0f - p) + 1e-6f;
            const float zpostvar  = 1.0f / (1.0f / zpvar + hess);
            const float zpostmean = zpred + zpostvar * grad;

            if (valid) {
                ll += y * logf(p + 1e-10f) + (1.0f - y) * logf(1.0f - p + 1e-10f);
            }
            zm = zpostmean;
            zv = zpostvar;
            sS[t][tid] = zpostmean;   // stage Z_filtered
            sC[t][tid] = zpostvar;    // stage Z_variance
        }
        __syncthreads();

        // --- cooperative store of staged outputs ---
        #pragma unroll
        for (int q = tid; q < NB * CT / 4; q += NB) {
            const int r  = q >> 2;
            const int c  = q & 3;
            const int nn = n0 + r;
            if (nn < N) {
                const int tb = c * 4;
                float4 vf, vv;
                vf.x = sS[tb + 0][r]; vf.y = sS[tb + 1][r];
                vf.z = sS[tb + 2][r]; vf.w = sS[tb + 3][r];
                vv.x = sC[tb + 0][r]; vv.y = sC[tb + 1][r];
                vv.z = sC[tb + 2][r]; vv.w = sC[tb + 3][r];
                const int gidx = nn * (TT / 4) + (t0 >> 2) + c;
                Zf4[gidx] = vf;
                Zv4[gidx] = vv;
            }
        }
        __syncthreads();  // protect LDS before next tile's load overwrites
    }

    // --- log-likelihood reduction: wave shuffle -> LDS -> one atomic/block ---
    #pragma unroll
    for (int off = 32; off > 0; off >>= 1) {
        ll += __shfl_down(ll, off, 64);
    }
    const int wid  = tid >> 6;
    const int lane = tid & 63;
    if (lane == 0) wave_ll[wid] = ll;
    __syncthreads();
    if (tid == 0) {
        float s = 0.0f;
        #pragma unroll
        for (int w = 0; w < NB / 64; ++w) s += wave_ll[w];
        atomicAdd(ll_out, s);
    }
}

extern "C" void kernel_launch(void* const* d_in, const int* in_sizes, int n_in,
                              void* d_out, int out_size, void* d_ws, size_t ws_size,
                              hipStream_t stream) {
    const int N = in_sizes[0];  // G is (N,1)

    const float* G   = (const float*)d_in[0];
    const float* S   = (const float*)d_in[1];
    const float* C   = (const float*)d_in[2];
    const float* Y   = (const float*)d_in[3];
    const float* L   = (const float*)d_in[4];
    const float* psi = (const float*)d_in[5];
    const float* gS  = (const float*)d_in[6];
    const float* gC  = (const float*)d_in[7];
    const float* gG  = (const float*)d_in[8];
    const float* gGS = (const float*)d_in[9];
    const float* gGC = (const float*)d_in[10];
    const float* gLw = (const float*)d_in[11];
    const float* lsZ = (const float*)d_in[12];
    const float* b0  = (const float*)d_in[13];
    const float* bZ  = (const float*)d_in[14];
    const float* bS  = (const float*)d_in[15];
    const float* bG  = (const float*)d_in[16];
    const float* bGS = (const float*)d_in[17];
    const float* bLw = (const float*)d_in[18];

    float* out = (float*)d_out;
    float* Zf = out;
    float* Zv = out + (size_t)N * TT;
    float* ll = out + (size_t)2 * N * TT;

    zero_ll_kernel<<<1, 1, 0, stream>>>(ll);

    const int blocks = (N + NB - 1) / NB;
    hmm_filter_kernel<<<blocks, NB, 0, stream>>>(
        G, S, C, Y, L, psi, gS, gC, gG, gGS, gGC, gLw, lsZ,
        b0, bZ, bS, bG, bGS, bLw, Zf, Zv, ll, N);
}